// Round 15
// baseline (434.054 us; speedup 1.0000x reference)
//
#include <hip/hip_runtime.h>
#include <hip/hip_bf16.h>

#define BB 16
#define NPG 512
#define CC 128
#define HH 8
#define LL 4
#define FFN 512
#define NCLS 4
#define DD 16
#define TT 513            // NPG + 1
#define EE 131072         // B * 8192
#define NNODES 8192       // B * NPG
#define ROWS (BB * TT)    // 8208 CSR rows keyed by (g, sl=query)
#define ECAP 64           // entries per bucket; Poisson(16), P(>=64) ~ 3e-22
#define SP 544            // padded s extent (34 tiles of 16)
#define BSTR 548          // full-s bias strip stride (floats); 548%32=4 -> 2-way (free)

static constexpr size_t XROWS = (size_t)BB * TT;   // 8208 (= 513 * 16 exactly)
static constexpr size_t XSZ   = XROWS * CC;        // 1,050,624
static constexpr size_t VTSZ  = (size_t)BB * HH * DD * SP;  // 1,114,112

typedef unsigned short ushort_t;
typedef __attribute__((ext_vector_type(8))) short short8;
typedef __attribute__((ext_vector_type(4))) float floatx4;

__device__ __forceinline__ float gelu_exact(float v) {
    return 0.5f * v * (1.0f + erff(v * 0.70710678118654752440f));
}
__device__ __forceinline__ ushort_t f2bf(float f) {
    union { float f; unsigned u; } c; c.f = f;
    unsigned u = c.u;
    return (ushort_t)((u + 0x7FFFu + ((u >> 16) & 1u)) >> 16);   // RNE
}
// XOR-swizzled LDS offset (16B granules); stride in shorts, multiple of 8
__device__ __forceinline__ int swz(int row, int col, int stride) {
    int kb = col >> 3;
    return row * stride + (((kb ^ (row & 7)) << 3) | (col & 7));
}

// ---- QKV stage (4-wave): hs (swizzled 16x128 ln1 tile) -> qb, kb, vt ----
__device__ __forceinline__ void qkv_stage4(const ushort_t* hs,
                                           const ushort_t* Wtq, const float* bq_,
                                           const ushort_t* Wtk, const float* bk_,
                                           const ushort_t* Wtv, const float* bv_,
                                           ushort_t* qb, ushort_t* kb, ushort_t* vt,
                                           int m0, int wave, int lq, int quad) {
    const short* hsS = (const short*)hs;
    int n0 = wave * 32;
    int c0 = n0 + lq, c1 = n0 + 16 + lq;
    const short* Ws[3] = {(const short*)Wtq, (const short*)Wtk, (const short*)Wtv};
    const float* bs[3] = {bq_, bk_, bv_};
    size_t rB0 = (size_t)(n0 + lq) * CC, rB1 = (size_t)(n0 + 16 + lq) * CC;

    #pragma unroll
    for (int m = 0; m < 3; ++m) {
        const short* W = Ws[m];
        floatx4 a0 = {0.f,0.f,0.f,0.f}, a1 = a0;
        #pragma unroll
        for (int k0 = 0; k0 < CC; k0 += 32) {
            short8 af = *(const short8*)(hsS + swz(lq, k0 + quad * 8, 128));
            short8 b0 = *(const short8*)(W + rB0 + k0 + quad * 8);
            short8 b1 = *(const short8*)(W + rB1 + k0 + quad * 8);
            a0 = __builtin_amdgcn_mfma_f32_16x16x32_bf16(af, b0, a0, 0, 0, 0);
            a1 = __builtin_amdgcn_mfma_f32_16x16x32_bf16(af, b1, a1, 0, 0, 0);
        }
        float bv0 = bs[m][c0], bv1 = bs[m][c1];
        #pragma unroll
        for (int rg = 0; rg < 4; ++rg) {
            int r = m0 + quad * 4 + rg;
            float v0 = a0[rg] + bv0;
            float v1 = a1[rg] + bv1;
            if (m == 0) {        // Q: fold 1/sqrt(D)=0.25 (exact)
                qb[(size_t)r * CC + c0] = f2bf(v0 * 0.25f);
                qb[(size_t)r * CC + c1] = f2bf(v1 * 0.25f);
            } else if (m == 1) { // K
                kb[(size_t)r * CC + c0] = f2bf(v0);
                kb[(size_t)r * CC + c1] = f2bf(v1);
            } else {             // V, written transposed VT[bh][d][s]
                int bg = r / TT;
                int s = r - bg * TT;
                vt[((size_t)(bg * HH + (c0 >> 4)) * DD + (c0 & 15)) * SP + s] = f2bf(v0);
                vt[((size_t)(bg * HH + (c1 >> 4)) * DD + (c1 & 15)) * SP + s] = f2bf(v1);
            }
        }
    }
}

// ---------------- merged: degree+CSR (blocks 0..511) | weight transpose (512..703) ----
__global__ __launch_bounds__(256) void deg_csr_tr_kernel(const int* __restrict__ ei,
                                                         const int* __restrict__ ea,
                                                         int* __restrict__ deg_in,
                                                         int* __restrict__ deg_out,
                                                         int* __restrict__ cnt,
                                                         int* __restrict__ ebuf,
                                                         const float* __restrict__ Wq,
                                                         const float* __restrict__ Wk,
                                                         const float* __restrict__ Wv,
                                                         const float* __restrict__ Wo,
                                                         const float* __restrict__ W1,
                                                         const float* __restrict__ W2,
                                                         ushort_t* __restrict__ wtqkvo,
                                                         ushort_t* __restrict__ wt1,
                                                         ushort_t* __restrict__ wt2) {
    int bid = blockIdx.x;
    int tid = threadIdx.x;
    if (bid < 512) {
        int e = bid * 256 + tid;
        int src = ei[e], dst = ei[EE + e];
        atomicAdd(&deg_out[src], 1);
        atomicAdd(&deg_in[dst], 1);
        int g = src >> 9;
        int sl = src - (g << 9) + 1;
        int dl = dst - (g << 9) + 1;
        int a = ea[e];
        a = (a < 0) ? 0 : (a > 9 ? 9 : a);
        a += 1;
        int row = g * TT + sl;
        int pos = atomicAdd(&cnt[row], 1);
        if (pos < ECAP) ebuf[(size_t)row * ECAP + pos] = dl | (a << 16);
        return;
    }
    // transpose tile z in [0,192): slot layout k*4+l (Q:0-3 K:4-7 V:8-11 O:12-15)
    int z = bid - 512;
    const float* src; ushort_t* dst; int K, N, tile;
    if (z < 64) {
        int zz = z >> 2; tile = z & 3;
        int k = zz >> 2, l = zz & 3;
        const float* s4[4] = {Wq, Wk, Wv, Wo};
        src = s4[k] + (size_t)l * CC * CC;
        dst = wtqkvo + (size_t)(k * 4 + l) * 16384;
        K = CC; N = CC;
    } else if (z < 128) {
        int l = (z - 64) >> 4; tile = (z - 64) & 15;
        src = W1 + (size_t)l * CC * FFN;
        dst = wt1 + (size_t)l * 65536;
        K = CC; N = FFN;
    } else {
        int l = (z - 128) >> 4; tile = (z - 128) & 15;
        src = W2 + (size_t)l * FFN * CC;
        dst = wt2 + (size_t)l * 65536;
        K = FFN; N = CC;
    }
    int tilesN = N >> 6;
    int k0 = (tile / tilesN) << 6;
    int n0 = (tile - (tile / tilesN) * tilesN) << 6;
    __shared__ float t[64][65];
    int c = tid & 63, rb = tid >> 6;
    #pragma unroll
    for (int kk = 0; kk < 64; kk += 4)
        t[kk + rb][c] = src[(size_t)(k0 + kk + rb) * N + n0 + c];
    __syncthreads();
    #pragma unroll
    for (int nn = 0; nn < 64; nn += 4)
        dst[(size_t)(n0 + nn + rb) * K + k0 + c] = f2bf(t[c][nn + rb]);
}

// ---------------- merged encode + ln1(L0) + QKV(L0): one 16-row tile per block ----
__global__ __launch_bounds__(256, 2) void encode_pre_kernel(const float* __restrict__ nf,
                                                            const float* __restrict__ Wn,
                                                            const float* __restrict__ bn,
                                                            const float* __restrict__ gt,
                                                            const float* __restrict__ ide,
                                                            const float* __restrict__ ode,
                                                            const int* __restrict__ deg_in,
                                                            const int* __restrict__ deg_out,
                                                            const float* __restrict__ ln1g_,
                                                            const float* __restrict__ ln1b_,
                                                            const ushort_t* __restrict__ wtqkvo,
                                                            const float* __restrict__ bq_,
                                                            const float* __restrict__ bk_,
                                                            const float* __restrict__ bv_,
                                                            float* __restrict__ x_,
                                                            ushort_t* __restrict__ qb,
                                                            ushort_t* __restrict__ kb,
                                                            ushort_t* __restrict__ vt) {
    int m0 = blockIdx.x * 16;
    int tid = threadIdx.x;
    int wave = tid >> 6, lane = tid & 63, lq = lane & 15, quad = lane >> 4;

    __shared__ ushort_t hs[16 * 128];
    __shared__ float sred[4][16][2];

    int n0 = wave * 32;
    int c0 = n0 + lq, c1 = n0 + 16 + lq;
    float w0[4], w1[4];
    #pragma unroll
    for (int rg = 0; rg < 4; ++rg) {
        int r = m0 + quad * 4 + rg;
        int b = r / TT;
        int t = r - b * TT;
        float v0, v1;
        if (t == 0) {
            v0 = gt[c0]; v1 = gt[c1];
        } else {
            int i = b * NPG + t - 1;
            float f0 = nf[i*3+0], f1 = nf[i*3+1], f2 = nf[i*3+2];
            v0 = bn[c0] + f0*Wn[0*CC + c0] + f1*Wn[1*CC + c0] + f2*Wn[2*CC + c0];
            v1 = bn[c1] + f0*Wn[0*CC + c1] + f1*Wn[1*CC + c1] + f2*Wn[2*CC + c1];
            int di = min(deg_in[i], 511);
            int dq = min(deg_out[i], 511);
            v0 += ide[(size_t)di * CC + c0] + ode[(size_t)dq * CC + c0];
            v1 += ide[(size_t)di * CC + c1] + ode[(size_t)dq * CC + c1];
        }
        x_[(size_t)r * CC + c0] = v0;
        x_[(size_t)r * CC + c1] = v1;
        w0[rg] = v0; w1[rg] = v1;
    }
    #pragma unroll
    for (int rg = 0; rg < 4; ++rg) {
        float s1 = w0[rg] + w1[rg];
        float s2 = w0[rg]*w0[rg] + w1[rg]*w1[rg];
        #pragma unroll
        for (int m = 1; m < 16; m <<= 1) {
            s1 += __shfl_xor(s1, m, 64);
            s2 += __shfl_xor(s2, m, 64);
        }
        if (lq == 0) { sred[wave][quad*4+rg][0] = s1; sred[wave][quad*4+rg][1] = s2; }
    }
    __syncthreads();
    float g0 = ln1g_[c0], g1 = ln1g_[c1], lb0 = ln1b_[c0], lb1 = ln1b_[c1];
    #pragma unroll
    for (int rg = 0; rg < 4; ++rg) {
        int row = quad * 4 + rg;
        float S1 = sred[0][row][0] + sred[1][row][0] + sred[2][row][0] + sred[3][row][0];
        float S2 = sred[0][row][1] + sred[1][row][1] + sred[2][row][1] + sred[3][row][1];
        float mn = S1 * (1.0f/CC);
        float var = S2 * (1.0f/CC) - mn * mn;
        float rs = rsqrtf(var + 1e-5f);
        hs[swz(row, c0, 128)] = f2bf((w0[rg] - mn) * rs * g0 + lb0);
        hs[swz(row, c1, 128)] = f2bf((w1[rg] - mn) * rs * g1 + lb1);
    }
    __syncthreads();
    qkv_stage4(hs, wtqkvo, bq_,
               wtqkvo + (size_t)4 * 16384, bk_,
               wtqkvo + (size_t)8 * 16384, bv_,
               qb, kb, vt, m0, wave, lq, quad);
}

// ---------------- mega kernel (4 waves): o-proj+res+ln2+ffn1+gelu+ffn2+res
//   + (ln1next + QKVnext) when doQKV, + folded head on the last layer ----
__global__ __launch_bounds__(256, 2) void mega_kernel(const ushort_t* __restrict__ obf,
                                                   const ushort_t* __restrict__ WtO,
                                                   const float* __restrict__ bo_,
                                                   const float* __restrict__ ln2g_,
                                                   const float* __restrict__ ln2b_,
                                                   const ushort_t* __restrict__ Wt1_,
                                                   const float* __restrict__ b1_,
                                                   const ushort_t* __restrict__ Wt2_,
                                                   const float* __restrict__ b2_,
                                                   const float* __restrict__ ln1g_,
                                                   const float* __restrict__ ln1b_,
                                                   const ushort_t* __restrict__ Wtq,
                                                   const float* __restrict__ bq_,
                                                   const ushort_t* __restrict__ Wtk,
                                                   const float* __restrict__ bk_,
                                                   const ushort_t* __restrict__ Wtv,
                                                   const float* __restrict__ bv_,
                                                   const float* __restrict__ nfg,
                                                   const float* __restrict__ nfb,
                                                   const float* __restrict__ Wc1,
                                                   const float* __restrict__ bc1,
                                                   const float* __restrict__ Wc2,
                                                   const float* __restrict__ bc2,
                                                   float* __restrict__ x_,
                                                   ushort_t* __restrict__ qb,
                                                   ushort_t* __restrict__ kb,
                                                   ushort_t* __restrict__ vt,
                                                   float* __restrict__ out,
                                                   int doQKV) {
    int m0 = blockIdx.x * 16;
    int tid = threadIdx.x;
    int wave = tid >> 6, lane = tid & 63, lq = lane & 15, quad = lane >> 4;

    __shared__ ushort_t hs[16 * 128];    // ln2(h) tile then ln1next tile, swizzled
    __shared__ ushort_t ms[16 * 512];    // gelu(mid) tile, swizzled
    __shared__ float sred[4][16][2];

    int n0 = wave * 32;
    int c0 = n0 + lq, c1 = n0 + 16 + lq;
    float vv0[4], vv1[4];   // o-proj residual, reused in ffn2 epilogue

    // ---- stage 1: o-proj (16x32 per wave, K=128) + res + ln2 -> hs ----
    {
        const short* Ab = (const short*)obf;
        const short* W = (const short*)WtO;
        size_t rowA = (size_t)(m0 + lq) * CC;
        size_t rB0 = (size_t)(n0 + lq) * CC, rB1 = (size_t)(n0 + 16 + lq) * CC;
        floatx4 a0 = {0.f,0.f,0.f,0.f}, a1 = a0;
        #pragma unroll
        for (int k0 = 0; k0 < CC; k0 += 32) {
            short8 af = *(const short8*)(Ab + rowA + k0 + quad * 8);
            short8 b0 = *(const short8*)(W + rB0 + k0 + quad * 8);
            short8 b1 = *(const short8*)(W + rB1 + k0 + quad * 8);
            a0 = __builtin_amdgcn_mfma_f32_16x16x32_bf16(af, b0, a0, 0, 0, 0);
            a1 = __builtin_amdgcn_mfma_f32_16x16x32_bf16(af, b1, a1, 0, 0, 0);
        }
        float bv0 = bo_[c0], bv1 = bo_[c1];
        #pragma unroll
        for (int rg = 0; rg < 4; ++rg) {
            int r = m0 + quad * 4 + rg;
            vv0[rg] = a0[rg] + bv0 + x_[(size_t)r * CC + c0];
            vv1[rg] = a1[rg] + bv1 + x_[(size_t)r * CC + c1];
        }
        #pragma unroll
        for (int rg = 0; rg < 4; ++rg) {
            float s1 = vv0[rg] + vv1[rg];
            float s2 = vv0[rg]*vv0[rg] + vv1[rg]*vv1[rg];
            #pragma unroll
            for (int m = 1; m < 16; m <<= 1) {
                s1 += __shfl_xor(s1, m, 64);
                s2 += __shfl_xor(s2, m, 64);
            }
            if (lq == 0) { sred[wave][quad*4+rg][0] = s1; sred[wave][quad*4+rg][1] = s2; }
        }
        __syncthreads();
        float g0 = ln2g_[c0], g1 = ln2g_[c1], lb0 = ln2b_[c0], lb1 = ln2b_[c1];
        #pragma unroll
        for (int rg = 0; rg < 4; ++rg) {
            int row = quad * 4 + rg;
            float S1 = sred[0][row][0] + sred[1][row][0] + sred[2][row][0] + sred[3][row][0];
            float S2 = sred[0][row][1] + sred[1][row][1] + sred[2][row][1] + sred[3][row][1];
            float mn = S1 * (1.0f/CC);
            float var = S2 * (1.0f/CC) - mn * mn;
            float rs = rsqrtf(var + 1e-5f);
            hs[swz(row, c0, 128)] = f2bf((vv0[rg] - mn) * rs * g0 + lb0);
            hs[swz(row, c1, 128)] = f2bf((vv1[rg] - mn) * rs * g1 + lb1);
        }
    }
    __syncthreads();

    // ---- stage 2: ffn1 (wave covers mid cols wave*128..+127, K=128) + gelu -> ms ----
    {
        const short* hsS = (const short*)hs;
        const short* W = (const short*)Wt1_;
        #pragma unroll
        for (int nt = 0; nt < 4; ++nt) {
            int n = wave * 128 + nt * 32;
            size_t rB0 = (size_t)(n + lq) * CC, rB1 = (size_t)(n + 16 + lq) * CC;
            floatx4 a0 = {0.f,0.f,0.f,0.f}, a1 = a0;
            #pragma unroll
            for (int k0 = 0; k0 < CC; k0 += 32) {
                short8 af = *(const short8*)(hsS + swz(lq, k0 + quad * 8, 128));
                short8 b0 = *(const short8*)(W + rB0 + k0 + quad * 8);
                short8 b1 = *(const short8*)(W + rB1 + k0 + quad * 8);
                a0 = __builtin_amdgcn_mfma_f32_16x16x32_bf16(af, b0, a0, 0, 0, 0);
                a1 = __builtin_amdgcn_mfma_f32_16x16x32_bf16(af, b1, a1, 0, 0, 0);
            }
            float bb0 = b1_[n + lq], bb1 = b1_[n + 16 + lq];
            #pragma unroll
            for (int rg = 0; rg < 4; ++rg) {
                int row = quad * 4 + rg;
                ms[swz(row, n + lq, 512)]      = f2bf(gelu_exact(a0[rg] + bb0));
                ms[swz(row, n + 16 + lq, 512)] = f2bf(gelu_exact(a1[rg] + bb1));
            }
        }
    }
    __syncthreads();

    // ---- stage 3: ffn2 (16x32 per wave, K=512 from ms) + res ----
    float w0[4], w1[4];
    {
        const short* msS = (const short*)ms;
        const short* W = (const short*)Wt2_;
        size_t rB0 = (size_t)(n0 + lq) * FFN, rB1 = (size_t)(n0 + 16 + lq) * FFN;
        floatx4 a0 = {0.f,0.f,0.f,0.f}, a1 = a0;
        #pragma unroll 8
        for (int k0 = 0; k0 < FFN; k0 += 32) {
            short8 af = *(const short8*)(msS + swz(lq, k0 + quad * 8, 512));
            short8 b0 = *(const short8*)(W + rB0 + k0 + quad * 8);
            short8 b1 = *(const short8*)(W + rB1 + k0 + quad * 8);
            a0 = __builtin_amdgcn_mfma_f32_16x16x32_bf16(af, b0, a0, 0, 0, 0);
            a1 = __builtin_amdgcn_mfma_f32_16x16x32_bf16(af, b1, a1, 0, 0, 0);
        }
        float bv0 = b2_[c0], bv1 = b2_[c1];
        #pragma unroll
        for (int rg = 0; rg < 4; ++rg) {
            int r = m0 + quad * 4 + rg;
            w0[rg] = a0[rg] + bv0 + vv0[rg];
            w1[rg] = a1[rg] + bv1 + vv1[rg];
            x_[(size_t)r * CC + c0] = w0[rg];
            x_[(size_t)r * CC + c1] = w1[rg];
        }
    }

    if (doQKV) {
        // ln1(next layer) -> hs, then QKV
        #pragma unroll
        for (int rg = 0; rg < 4; ++rg) {
            float s1 = w0[rg] + w1[rg];
            float s2 = w0[rg]*w0[rg] + w1[rg]*w1[rg];
            #pragma unroll
            for (int m = 1; m < 16; m <<= 1) {
                s1 += __shfl_xor(s1, m, 64);
                s2 += __shfl_xor(s2, m, 64);
            }
            if (lq == 0) { sred[wave][quad*4+rg][0] = s1; sred[wave][quad*4+rg][1] = s2; }
        }
        __syncthreads();
        float g0 = ln1g_[c0], g1 = ln1g_[c1], lb0 = ln1b_[c0], lb1 = ln1b_[c1];
        #pragma unroll
        for (int rg = 0; rg < 4; ++rg) {
            int row = quad * 4 + rg;
            float S1 = sred[0][row][0] + sred[1][row][0] + sred[2][row][0] + sred[3][row][0];
            float S2 = sred[0][row][1] + sred[1][row][1] + sred[2][row][1] + sred[3][row][1];
            float mn = S1 * (1.0f/CC);
            float var = S2 * (1.0f/CC) - mn * mn;
            float rs = rsqrtf(var + 1e-5f);
            hs[swz(row, c0, 128)] = f2bf((w0[rg] - mn) * rs * g0 + lb0);
            hs[swz(row, c1, 128)] = f2bf((w1[rg] - mn) * rs * g1 + lb1);
        }
        __syncthreads();
        qkv_stage4(hs, Wtq, bq_, Wtk, bk_, Wtv, bv_, qb, kb, vt, m0, wave, lq, quad);
        return;
    }

    // ---- last layer: folded head for the graph-token row in this tile (if any) ----
    int gb = (m0 + TT - 1) / TT;          // candidate graph whose token row >= m0
    int rgt = gb * TT;
    if (gb >= BB || rgt >= m0 + 16) return;
    int hb = rgt - m0;                    // row within tile

    __syncthreads();                      // all waves done reading ms; reuse as scratch
    float* hrow = (float*)ms;             // 128
    float* xfs  = hrow + CC;              // 128
    float* c1s  = xfs + CC;               // 64
    float* red  = c1s + 64;               // 4
    #pragma unroll
    for (int rg = 0; rg < 4; ++rg) {
        if (quad * 4 + rg == hb) { hrow[c0] = w0[rg]; hrow[c1] = w1[rg]; }
    }
    __syncthreads();

    {
        int c = tid;
        float v = 0.f, s1 = 0.f, s2 = 0.f;
        if (c < CC) { v = hrow[c]; s1 = v; s2 = v * v; }
        #pragma unroll
        for (int m = 32; m >= 1; m >>= 1) {
            s1 += __shfl_xor(s1, m, 64);
            s2 += __shfl_xor(s2, m, 64);
        }
        int w = c >> 6;
        if (c < CC && (c & 63) == 0) { red[w*2] = s1; red[w*2+1] = s2; }
        __syncthreads();
        if (c < CC) {
            float S1 = red[0] + red[2], S2 = red[1] + red[3];
            float mn = S1 * (1.0f/CC);
            float var = S2 * (1.0f/CC) - mn * mn;
            float rs = rsqrtf(var + 1e-5f);
            xfs[c] = (v - mn) * rs * nfg[c] + nfb[c];
        }
        __syncthreads();
        if (c < 64) {
            float acc = bc1[c];
            #pragma unroll 4
            for (int k = 0; k < CC; ++k) acc = fmaf(xfs[k], Wc1[(size_t)k * 64 + c], acc);
            c1s[c] = gelu_exact(acc);
        }
        __syncthreads();
        if (c < NCLS) {
            float acc = bc2[c];
            #pragma unroll 4
            for (int j = 0; j < 64; ++j) acc = fmaf(c1s[j], Wc2[(size_t)j * NCLS + c], acc);
            out[(size_t)gb * NCLS + c] = acc;
        }
    }
}

// ---------------- MFMA fused attention: one block per (bh, 16-query tile) ----------------
// Single full-s bias strip [16 q][548 s] built ONCE (one zero, one unfiltered
// scatter, one barrier pair); sp loop runs 17 iterations uninterrupted with
// depth-1 K/V prefetch. 35 KB LDS -> 4 blocks/CU.
__global__ __launch_bounds__(256) void attn_kernel(const ushort_t* __restrict__ qb,
                                                   const ushort_t* __restrict__ kb,
                                                   const ushort_t* __restrict__ vt,
                                                   const int* __restrict__ cnt,
                                                   const int* __restrict__ ebuf,
                                                   const float* __restrict__ ebt,
                                                   const float* __restrict__ vnode,
                                                   ushort_t* __restrict__ ob) {
    int bh = blockIdx.x;
    int qt = blockIdx.y;
    int b = bh >> 3, h = bh & (HH - 1);
    int tid = threadIdx.x;
    int wave = tid >> 6, lane = tid & 63, lq = lane & 15, quad = lane >> 4;

    __shared__ float arena[16 * BSTR];   // 35,072 B strip [q][s] (aliased by epilogue)
    float* bstrip = arena;

    // hoisted global loads (latency overlaps strip build)
    int qg = qt * 16 + lq;
    int qr = qg < TT ? qg : TT - 1;
    short8 qf = {0,0,0,0,0,0,0,0};
    if (quad < 2)
        qf = *(const short8*)(qb + ((size_t)(b * TT + qr)) * CC + h * DD + quad * 8);
    float vbh = vnode[h];
    int ql = tid >> 4, e0 = tid & 15;
    int qs = qt * 16 + ql;
    int crow = b * TT + (qs < TT ? qs : 0);
    int cn = (qs > 0 && qs < TT) ? min(cnt[crow], ECAP) : 0;

    const short* kbS = (const short*)kb;
    const short* vtS = (const short*)(vt + (size_t)bh * DD * SP);

    // prologue prefetch for sp = wave
    int sp = wave;
    short8 af0, af1, vf;
    {
        int st0 = sp * 2, st1 = sp * 2 + 1;
        int kr0 = min(b * TT + st0 * 16 + lq, (int)XROWS - 1);
        int kr1 = min(b * TT + st1 * 16 + lq, (int)XROWS - 1);
        af0 = (short8){0,0,0,0,0,0,0,0}; af1 = af0;
        if (quad < 2) {
            af0 = *(const short8*)(kbS + (size_t)kr0 * CC + h * DD + quad * 8);
            af1 = *(const short8*)(kbS + (size_t)kr1 * CC + h * DD + quad * 8);
        }
        vf = *(const short8*)(vtS + (size_t)lq * SP + sp * 32 + quad * 8);
    }

    // build bias strip: zero, then vnode row + unfiltered CSR scatter
    for (int i = tid; i < 16 * BSTR / 4; i += 256)
        ((float4*)bstrip)[i] = make_float4(0.f, 0.f, 0.f, 0.f);
    __syncthreads();
    if (tid < 16) {
        int q = qt * 16 + tid;
        if (q > 0 && q < TT) bstrip[tid * BSTR] = vbh;   // s==0 vnode bias
    }
    for (int j = e0; j < cn; j += 16) {
        int e = ebuf[(size_t)crow * ECAP + j];
        int dl = e & 0xFFFF, a = e >> 16;                // dl in 1..512 < BSTR
        atomicAdd(&bstrip[ql * BSTR + dl], ebt[a * 8 + h]);
    }
    __syncthreads();

    floatx4 oacc = {0.f, 0.f, 0.f, 0.f};
    float lsum = 0.f;

    for (; sp < 17; sp += 4) {
        int spn = sp + 4;
        short8 nf0 = {0,0,0,0,0,0,0,0}, nf1 = nf0, nvf = nf0;
        if (spn < 17) {
            int st0 = spn * 2, st1 = spn * 2 + 1;
            int kr0 = min(b * TT + st0 * 16 + lq, (int)XROWS - 1);
            int kr1 = min(b * TT + st1 * 16 + lq, (int)XROWS - 1);
            if (quad < 2) {
                nf0 = *(const short8*)(kbS + (size_t)kr0 * CC + h * DD + quad * 8);
                nf1 = *(const short8*)(kbS + (size_t)kr1 * CC + h * DD + quad * 8);
            }
            nvf = *(const short8*)(vtS + (size_t)lq * SP + spn * 32 + quad * 8);
        }

        unsigned pw[2][2];
        #pragma unroll
        for (int t = 0; t < 2; ++t) {
            int st = sp * 2 + t;
            floatx4 c = __builtin_amdgcn_mfma_f32_16x16x32_bf16(
                t ? af1 : af0, qf, (floatx4){0.f, 0.f, 0.f, 0.f}, 0, 0, 0);
            float4 bi = *(const float4*)(bstrip + lq * BSTR + st * 16 + quad * 4);
            float biv[4] = {bi.x, bi.y, bi.z, bi.w};
            float pr[4];
            #pragma unroll
            for (int rg = 0; rg < 4; ++rg) {
                int s = st * 16 + quad * 4 + rg;
                float p = 0.f;
                if (s < TT) p = __expf(c[rg] + biv[rg]);
                lsum += p;
                pr[rg] = p;
            }
            pw[t][0] = (unsigned)f2bf(pr[0]) | ((unsigned)f2bf(pr[1]) << 16);
            pw[t][1] = (unsigned)f2bf(pr[2]) | ((unsigned)f2bf(pr[3]) << 16);
        }
        // C-layout -> B-layout: quad permutation among lanes sharing lq
        int srcA = lq + (((2 * quad) & 3) << 4);
        int srcB = lq + (((2 * quad + 1) & 3) << 4);
        int a00 = __shfl((int)pw[0][0], srcA, 64);
        int a01 = __shfl((int)pw[0][1], srcA, 64);
        int a10 = __shfl((int)pw[1][0], srcA, 64);
        int a11 = __shfl((int)pw[1][1], srcA, 64);
        int b00 = __shfl((int)pw[0][0], srcB, 64);
        int b01 = __shfl((int)pw[0][1], srcB, 64);
        int b10 = __shfl((int)pw[1][0], srcB, 64);
        int b11 = __shfl((int)pw[1][1], srcB, 64);
        union { int u[4]; short8 s8; } pu;
        bool lo = quad < 2;
        pu.u[0] = lo ? a00 : a10;
        pu.u[1] = lo ? a01 : a11;
        pu.u[2] = lo ? b00 : b10;
        pu.u[3] = lo ? b01 : b11;
        oacc = __builtin_amdgcn_mfma_f32_16x16x32_bf16(vf, pu.s8, oacc, 0, 0, 0);

        af0 = nf0; af1 = nf1; vf = nvf;
    }
    __syncthreads();   // strip reads done; arena reused by epilogue

    lsum += __shfl_xor(lsum, 16, 64);
    lsum += __shfl_xor(lsum, 32, 64);
    float* redw = arena;
    float* lsumS = arena + 1088;
    #pragma unroll
    for (int rg = 0; rg < 4; ++rg)
        redw[wave * 272 + (quad * 4 + rg) * 17 + lq] = oacc[rg];
    if (quad == 0) lsumS[wave * 16 + lq] = lsum;
    __syncthreads();

    {
        int q = tid >> 4, d = tid & 15;
        float o = 0.f, L = 0.f;
        #pragma unroll
        for (int w = 0; w < 4; ++w) {
            o += redw[w * 272 + d * 17 + q];
            L += lsumS[w * 16 + q];
        }
        int qq = qt * 16 + q;
        if (qq < TT)
            ob[((size_t)(b * TT + qq)) * CC + h * DD + d] = f2bf(o / L);
    }
}

extern "C" void kernel_launch(void* const* d_in, const int* in_sizes, int n_in,
                              void* d_out, int out_size, void* d_ws, size_t ws_size,
                              hipStream_t stream) {
    const float* node_feats = (const float*)d_in[0];
    const int*   edge_index = (const int*)d_in[1];
    const int*   edge_attr  = (const int*)d_in[2];
    const float* W_node  = (const float*)d_in[4];
    const float* b_node  = (const float*)d_in[5];
    const float* g_token = (const float*)d_in[6];
    const float* ebt     = (const float*)d_in[7];
    const float* ide     = (const float*)d_in[8];
    const float* ode     = (const float*)d_in[9];
    const float* vnode   = (const float*)d_in[10];
    const float* Wq = (const float*)d_in[11];
    const float* bq = (const float*)d_in[12];
    const float* Wk = (const float*)d_in[13];
    const float* bk = (const float*)d_in[14];
    const float* Wv = (const float*)d_in[15];
    const float* bv = (const float*)d_in[16];
    const float* Wo = (const float*)d_in[17];
    const float* bo = (const float*)d_in[18];
    const float* ln1g = (const float*)d_in[19];
    const float* ln1b = (const float*)d_in[20];
    const float* ln2g = (const float*)d_in[21];
    const float* ln2b = (const float*)d_in[22];
    const float* W1 = (const float*)d_in[23];
    const float* b1 = (const float*)d_in[24];
    const float* W2 = (const float*)d_in[25];
    const float* b2 = (const float*)d_in[26];
    const float* nfg = (const float*)d_in[27];
    const float* nfb = (const float*)d_in[28];
    const float* Wc1 = (const float*)d_in[29];
    const float* bc1 = (const float*)d_in[30];
    const float* Wc2 = (const float*)d_in[31];
    const float* bc2 = (const float*)d_in[32];
    float* out = (float*)d_out;

    // ---- workspace (all chunks 16B-aligned) ----
    char* base = (char*)d_ws;
    float* x      = (float*)base;     base += XSZ * 4;
    ushort_t* qb  = (ushort_t*)base;  base += XSZ * 2;
    ushort_t* kb  = (ushort_t*)base;  base += XSZ * 2;
    ushort_t* vt  = (ushort_t*)base;  base += VTSZ * 2;
    ushort_t* obf = (ushort_t*)base;  base += XSZ * 2;
    ushort_t* wtqkvo = (ushort_t*)base; base += (size_t)16 * 16384 * 2;
    ushort_t* wt1 = (ushort_t*)base;  base += (size_t)4 * 65536 * 2;
    ushort_t* wt2 = (ushort_t*)base;  base += (size_t)4 * 65536 * 2;
    int* deg_in  = (int*)base;        base += NNODES * 4;
    int* deg_out = (int*)base;        base += NNODES * 4;
    int* cnt     = (int*)base;        base += (size_t)ROWS * 4;
    int* ebuf    = (int*)base;        base += (size_t)ROWS * ECAP * 4;

    const int MT16 = (int)(XROWS / 16);   // 513 m-tiles of 16 rows (exact)

    hipMemsetAsync(deg_in, 0, (size_t)(2 * NNODES + ROWS) * 4, stream);
    deg_csr_tr_kernel<<<512 + 192, 256, 0, stream>>>(
        edge_index, edge_attr, deg_in, deg_out, cnt, ebuf,
        Wq, Wk, Wv, Wo, W1, W2, wtqkvo, wt1, wt2);

    encode_pre_kernel<<<MT16, 256, 0, stream>>>(
        node_feats, W_node, b_node, g_token, ide, ode, deg_in, deg_out,
        ln1g, ln1b, wtqkvo, bq, bk, bv, x, qb, kb, vt);

    for (int l = 0; l < LL; ++l) {
        attn_kernel<<<dim3(BB*HH, 33), 256, 0, stream>>>(
            qb, kb, vt, cnt, ebuf, ebt, vnode, obf);

        int ln = (l + 1) % LL;   // next layer (unused when l==LL-1)
        mega_kernel<<<MT16, 256, 0, stream>>>(
            obf,
            wtqkvo + (size_t)(12 + l)*16384, bo + l*CC,
            ln2g + l*CC, ln2b + l*CC,
            wt1 + (size_t)l*65536, b1 + l*FFN,
            wt2 + (size_t)l*65536, b2 + l*CC,
            ln1g + ln*CC, ln1b + ln*CC,
            wtqkvo + (size_t)(0 + ln)*16384, bq + ln*CC,
            wtqkvo + (size_t)(4 + ln)*16384, bk + ln*CC,
            wtqkvo + (size_t)(8 + ln)*16384, bv + ln*CC,
            nfg, nfb, Wc1, bc1, Wc2, bc2,
            x, qb, kb, vt, out,
            (l < LL-1) ? 1 : 0);
    }
}

// Round 16
// 420.341 us; speedup vs baseline: 1.0326x; 1.0326x over previous
//
#include <hip/hip_runtime.h>
#include <hip/hip_bf16.h>

#define BB 16
#define NPG 512
#define CC 128
#define HH 8
#define LL 4
#define FFN 512
#define NCLS 4
#define DD 16
#define TT 513            // NPG + 1
#define EE 131072         // B * 8192
#define NNODES 8192       // B * NPG
#define ROWS (BB * TT)    // 8208 CSR rows keyed by (g, sl=query)
#define ECAP 64           // entries per bucket; Poisson(16), P(>=64) ~ 3e-22
#define SP 544            // padded s extent (34 tiles of 16)
#define BSTR 292          // bias strip stride (floats), mult of 4 for b128

static constexpr size_t XROWS = (size_t)BB * TT;   // 8208 (= 513 * 16 exactly)
static constexpr size_t XSZ   = XROWS * CC;        // 1,050,624
static constexpr size_t VTSZ  = (size_t)BB * HH * DD * SP;  // 1,114,112

typedef unsigned short ushort_t;
typedef __attribute__((ext_vector_type(8))) short short8;
typedef __attribute__((ext_vector_type(4))) float floatx4;

__device__ __forceinline__ float gelu_exact(float v) {
    return 0.5f * v * (1.0f + erff(v * 0.70710678118654752440f));
}
__device__ __forceinline__ ushort_t f2bf(float f) {
    union { float f; unsigned u; } c; c.f = f;
    unsigned u = c.u;
    return (ushort_t)((u + 0x7FFFu + ((u >> 16) & 1u)) >> 16);   // RNE
}
// XOR-swizzled LDS offset (16B granules); stride in shorts, multiple of 8
__device__ __forceinline__ int swz(int row, int col, int stride) {
    int kb = col >> 3;
    return row * stride + (((kb ^ (row & 7)) << 3) | (col & 7));
}

// ---- QKV stage (4-wave): hs (swizzled 16x128 ln1 tile) -> qb, kb, vt ----
__device__ __forceinline__ void qkv_stage4(const ushort_t* hs,
                                           const ushort_t* Wtq, const float* bq_,
                                           const ushort_t* Wtk, const float* bk_,
                                           const ushort_t* Wtv, const float* bv_,
                                           ushort_t* qb, ushort_t* kb, ushort_t* vt,
                                           int m0, int wave, int lq, int quad) {
    const short* hsS = (const short*)hs;
    int n0 = wave * 32;
    int c0 = n0 + lq, c1 = n0 + 16 + lq;
    const short* Ws[3] = {(const short*)Wtq, (const short*)Wtk, (const short*)Wtv};
    const float* bs[3] = {bq_, bk_, bv_};
    size_t rB0 = (size_t)(n0 + lq) * CC, rB1 = (size_t)(n0 + 16 + lq) * CC;

    #pragma unroll
    for (int m = 0; m < 3; ++m) {
        const short* W = Ws[m];
        floatx4 a0 = {0.f,0.f,0.f,0.f}, a1 = a0;
        #pragma unroll
        for (int k0 = 0; k0 < CC; k0 += 32) {
            short8 af = *(const short8*)(hsS + swz(lq, k0 + quad * 8, 128));
            short8 b0 = *(const short8*)(W + rB0 + k0 + quad * 8);
            short8 b1 = *(const short8*)(W + rB1 + k0 + quad * 8);
            a0 = __builtin_amdgcn_mfma_f32_16x16x32_bf16(af, b0, a0, 0, 0, 0);
            a1 = __builtin_amdgcn_mfma_f32_16x16x32_bf16(af, b1, a1, 0, 0, 0);
        }
        float bv0 = bs[m][c0], bv1 = bs[m][c1];
        #pragma unroll
        for (int rg = 0; rg < 4; ++rg) {
            int r = m0 + quad * 4 + rg;
            float v0 = a0[rg] + bv0;
            float v1 = a1[rg] + bv1;
            if (m == 0) {        // Q: fold 1/sqrt(D)=0.25 (exact)
                qb[(size_t)r * CC + c0] = f2bf(v0 * 0.25f);
                qb[(size_t)r * CC + c1] = f2bf(v1 * 0.25f);
            } else if (m == 1) { // K
                kb[(size_t)r * CC + c0] = f2bf(v0);
                kb[(size_t)r * CC + c1] = f2bf(v1);
            } else {             // V, written transposed VT[bh][d][s]
                int bg = r / TT;
                int s = r - bg * TT;
                vt[((size_t)(bg * HH + (c0 >> 4)) * DD + (c0 & 15)) * SP + s] = f2bf(v0);
                vt[((size_t)(bg * HH + (c1 >> 4)) * DD + (c1 & 15)) * SP + s] = f2bf(v1);
            }
        }
    }
}

// ---------------- merged: degree+CSR (blocks 0..511) | weight transpose (512..703) ----
__global__ __launch_bounds__(256) void deg_csr_tr_kernel(const int* __restrict__ ei,
                                                         const int* __restrict__ ea,
                                                         int* __restrict__ deg_in,
                                                         int* __restrict__ deg_out,
                                                         int* __restrict__ cnt,
                                                         int* __restrict__ ebuf,
                                                         const float* __restrict__ Wq,
                                                         const float* __restrict__ Wk,
                                                         const float* __restrict__ Wv,
                                                         const float* __restrict__ Wo,
                                                         const float* __restrict__ W1,
                                                         const float* __restrict__ W2,
                                                         ushort_t* __restrict__ wtqkvo,
                                                         ushort_t* __restrict__ wt1,
                                                         ushort_t* __restrict__ wt2) {
    int bid = blockIdx.x;
    int tid = threadIdx.x;
    if (bid < 512) {
        int e = bid * 256 + tid;
        int src = ei[e], dst = ei[EE + e];
        atomicAdd(&deg_out[src], 1);
        atomicAdd(&deg_in[dst], 1);
        int g = src >> 9;
        int sl = src - (g << 9) + 1;
        int dl = dst - (g << 9) + 1;
        int a = ea[e];
        a = (a < 0) ? 0 : (a > 9 ? 9 : a);
        a += 1;
        int row = g * TT + sl;
        int pos = atomicAdd(&cnt[row], 1);
        if (pos < ECAP) ebuf[(size_t)row * ECAP + pos] = dl | (a << 16);
        return;
    }
    // transpose tile z in [0,192): slot layout k*4+l (Q:0-3 K:4-7 V:8-11 O:12-15)
    int z = bid - 512;
    const float* src; ushort_t* dst; int K, N, tile;
    if (z < 64) {
        int zz = z >> 2; tile = z & 3;
        int k = zz >> 2, l = zz & 3;
        const float* s4[4] = {Wq, Wk, Wv, Wo};
        src = s4[k] + (size_t)l * CC * CC;
        dst = wtqkvo + (size_t)(k * 4 + l) * 16384;
        K = CC; N = CC;
    } else if (z < 128) {
        int l = (z - 64) >> 4; tile = (z - 64) & 15;
        src = W1 + (size_t)l * CC * FFN;
        dst = wt1 + (size_t)l * 65536;
        K = CC; N = FFN;
    } else {
        int l = (z - 128) >> 4; tile = (z - 128) & 15;
        src = W2 + (size_t)l * FFN * CC;
        dst = wt2 + (size_t)l * 65536;
        K = FFN; N = CC;
    }
    int tilesN = N >> 6;
    int k0 = (tile / tilesN) << 6;
    int n0 = (tile - (tile / tilesN) * tilesN) << 6;
    __shared__ float t[64][65];
    int c = tid & 63, rb = tid >> 6;
    #pragma unroll
    for (int kk = 0; kk < 64; kk += 4)
        t[kk + rb][c] = src[(size_t)(k0 + kk + rb) * N + n0 + c];
    __syncthreads();
    #pragma unroll
    for (int nn = 0; nn < 64; nn += 4)
        dst[(size_t)(n0 + nn + rb) * K + k0 + c] = f2bf(t[c][nn + rb]);
}

// ---------------- merged encode + ln1(L0) + QKV(L0): one 16-row tile per block ----
__global__ __launch_bounds__(256) void encode_pre_kernel(const float* __restrict__ nf,
                                                         const float* __restrict__ Wn,
                                                         const float* __restrict__ bn,
                                                         const float* __restrict__ gt,
                                                         const float* __restrict__ ide,
                                                         const float* __restrict__ ode,
                                                         const int* __restrict__ deg_in,
                                                         const int* __restrict__ deg_out,
                                                         const float* __restrict__ ln1g_,
                                                         const float* __restrict__ ln1b_,
                                                         const ushort_t* __restrict__ wtqkvo,
                                                         const float* __restrict__ bq_,
                                                         const float* __restrict__ bk_,
                                                         const float* __restrict__ bv_,
                                                         float* __restrict__ x_,
                                                         ushort_t* __restrict__ qb,
                                                         ushort_t* __restrict__ kb,
                                                         ushort_t* __restrict__ vt) {
    int m0 = blockIdx.x * 16;
    int tid = threadIdx.x;
    int wave = tid >> 6, lane = tid & 63, lq = lane & 15, quad = lane >> 4;

    __shared__ ushort_t hs[16 * 128];
    __shared__ float sred[4][16][2];

    int n0 = wave * 32;
    int c0 = n0 + lq, c1 = n0 + 16 + lq;
    float w0[4], w1[4];
    #pragma unroll
    for (int rg = 0; rg < 4; ++rg) {
        int r = m0 + quad * 4 + rg;
        int b = r / TT;
        int t = r - b * TT;
        float v0, v1;
        if (t == 0) {
            v0 = gt[c0]; v1 = gt[c1];
        } else {
            int i = b * NPG + t - 1;
            float f0 = nf[i*3+0], f1 = nf[i*3+1], f2 = nf[i*3+2];
            v0 = bn[c0] + f0*Wn[0*CC + c0] + f1*Wn[1*CC + c0] + f2*Wn[2*CC + c0];
            v1 = bn[c1] + f0*Wn[0*CC + c1] + f1*Wn[1*CC + c1] + f2*Wn[2*CC + c1];
            int di = min(deg_in[i], 511);
            int dq = min(deg_out[i], 511);
            v0 += ide[(size_t)di * CC + c0] + ode[(size_t)dq * CC + c0];
            v1 += ide[(size_t)di * CC + c1] + ode[(size_t)dq * CC + c1];
        }
        x_[(size_t)r * CC + c0] = v0;
        x_[(size_t)r * CC + c1] = v1;
        w0[rg] = v0; w1[rg] = v1;
    }
    #pragma unroll
    for (int rg = 0; rg < 4; ++rg) {
        float s1 = w0[rg] + w1[rg];
        float s2 = w0[rg]*w0[rg] + w1[rg]*w1[rg];
        #pragma unroll
        for (int m = 1; m < 16; m <<= 1) {
            s1 += __shfl_xor(s1, m, 64);
            s2 += __shfl_xor(s2, m, 64);
        }
        if (lq == 0) { sred[wave][quad*4+rg][0] = s1; sred[wave][quad*4+rg][1] = s2; }
    }
    __syncthreads();
    float g0 = ln1g_[c0], g1 = ln1g_[c1], lb0 = ln1b_[c0], lb1 = ln1b_[c1];
    #pragma unroll
    for (int rg = 0; rg < 4; ++rg) {
        int row = quad * 4 + rg;
        float S1 = sred[0][row][0] + sred[1][row][0] + sred[2][row][0] + sred[3][row][0];
        float S2 = sred[0][row][1] + sred[1][row][1] + sred[2][row][1] + sred[3][row][1];
        float mn = S1 * (1.0f/CC);
        float var = S2 * (1.0f/CC) - mn * mn;
        float rs = rsqrtf(var + 1e-5f);
        hs[swz(row, c0, 128)] = f2bf((w0[rg] - mn) * rs * g0 + lb0);
        hs[swz(row, c1, 128)] = f2bf((w1[rg] - mn) * rs * g1 + lb1);
    }
    __syncthreads();
    qkv_stage4(hs, wtqkvo, bq_,
               wtqkvo + (size_t)4 * 16384, bk_,
               wtqkvo + (size_t)8 * 16384, bv_,
               qb, kb, vt, m0, wave, lq, quad);
}

// ---------------- mega kernel (4 waves): o-proj+res+ln2+ffn1+gelu+ffn2+res
//   + (ln1next + QKVnext) when doQKV, + folded head on the last layer ----
__global__ __launch_bounds__(256) void mega_kernel(const ushort_t* __restrict__ obf,
                                                   const ushort_t* __restrict__ WtO,
                                                   const float* __restrict__ bo_,
                                                   const float* __restrict__ ln2g_,
                                                   const float* __restrict__ ln2b_,
                                                   const ushort_t* __restrict__ Wt1_,
                                                   const float* __restrict__ b1_,
                                                   const ushort_t* __restrict__ Wt2_,
                                                   const float* __restrict__ b2_,
                                                   const float* __restrict__ ln1g_,
                                                   const float* __restrict__ ln1b_,
                                                   const ushort_t* __restrict__ Wtq,
                                                   const float* __restrict__ bq_,
                                                   const ushort_t* __restrict__ Wtk,
                                                   const float* __restrict__ bk_,
                                                   const ushort_t* __restrict__ Wtv,
                                                   const float* __restrict__ bv_,
                                                   const float* __restrict__ nfg,
                                                   const float* __restrict__ nfb,
                                                   const float* __restrict__ Wc1,
                                                   const float* __restrict__ bc1,
                                                   const float* __restrict__ Wc2,
                                                   const float* __restrict__ bc2,
                                                   float* __restrict__ x_,
                                                   ushort_t* __restrict__ qb,
                                                   ushort_t* __restrict__ kb,
                                                   ushort_t* __restrict__ vt,
                                                   float* __restrict__ out,
                                                   int doQKV) {
    int m0 = blockIdx.x * 16;
    int tid = threadIdx.x;
    int wave = tid >> 6, lane = tid & 63, lq = lane & 15, quad = lane >> 4;

    __shared__ ushort_t hs[16 * 128];    // ln2(h) tile then ln1next tile, swizzled
    __shared__ ushort_t ms[16 * 512];    // gelu(mid) tile, swizzled
    __shared__ float sred[4][16][2];

    int n0 = wave * 32;
    int c0 = n0 + lq, c1 = n0 + 16 + lq;
    float vv0[4], vv1[4];   // o-proj residual, reused in ffn2 epilogue

    // ---- stage 1: o-proj (16x32 per wave, K=128) + res + ln2 -> hs ----
    {
        const short* Ab = (const short*)obf;
        const short* W = (const short*)WtO;
        size_t rowA = (size_t)(m0 + lq) * CC;
        size_t rB0 = (size_t)(n0 + lq) * CC, rB1 = (size_t)(n0 + 16 + lq) * CC;
        floatx4 a0 = {0.f,0.f,0.f,0.f}, a1 = a0;
        #pragma unroll
        for (int k0 = 0; k0 < CC; k0 += 32) {
            short8 af = *(const short8*)(Ab + rowA + k0 + quad * 8);
            short8 b0 = *(const short8*)(W + rB0 + k0 + quad * 8);
            short8 b1 = *(const short8*)(W + rB1 + k0 + quad * 8);
            a0 = __builtin_amdgcn_mfma_f32_16x16x32_bf16(af, b0, a0, 0, 0, 0);
            a1 = __builtin_amdgcn_mfma_f32_16x16x32_bf16(af, b1, a1, 0, 0, 0);
        }
        float bv0 = bo_[c0], bv1 = bo_[c1];
        #pragma unroll
        for (int rg = 0; rg < 4; ++rg) {
            int r = m0 + quad * 4 + rg;
            vv0[rg] = a0[rg] + bv0 + x_[(size_t)r * CC + c0];
            vv1[rg] = a1[rg] + bv1 + x_[(size_t)r * CC + c1];
        }
        #pragma unroll
        for (int rg = 0; rg < 4; ++rg) {
            float s1 = vv0[rg] + vv1[rg];
            float s2 = vv0[rg]*vv0[rg] + vv1[rg]*vv1[rg];
            #pragma unroll
            for (int m = 1; m < 16; m <<= 1) {
                s1 += __shfl_xor(s1, m, 64);
                s2 += __shfl_xor(s2, m, 64);
            }
            if (lq == 0) { sred[wave][quad*4+rg][0] = s1; sred[wave][quad*4+rg][1] = s2; }
        }
        __syncthreads();
        float g0 = ln2g_[c0], g1 = ln2g_[c1], lb0 = ln2b_[c0], lb1 = ln2b_[c1];
        #pragma unroll
        for (int rg = 0; rg < 4; ++rg) {
            int row = quad * 4 + rg;
            float S1 = sred[0][row][0] + sred[1][row][0] + sred[2][row][0] + sred[3][row][0];
            float S2 = sred[0][row][1] + sred[1][row][1] + sred[2][row][1] + sred[3][row][1];
            float mn = S1 * (1.0f/CC);
            float var = S2 * (1.0f/CC) - mn * mn;
            float rs = rsqrtf(var + 1e-5f);
            hs[swz(row, c0, 128)] = f2bf((vv0[rg] - mn) * rs * g0 + lb0);
            hs[swz(row, c1, 128)] = f2bf((vv1[rg] - mn) * rs * g1 + lb1);
        }
    }
    __syncthreads();

    // ---- stage 2: ffn1 (wave covers mid cols wave*128..+127, K=128) + gelu -> ms ----
    {
        const short* hsS = (const short*)hs;
        const short* W = (const short*)Wt1_;
        #pragma unroll
        for (int nt = 0; nt < 4; ++nt) {
            int n = wave * 128 + nt * 32;
            size_t rB0 = (size_t)(n + lq) * CC, rB1 = (size_t)(n + 16 + lq) * CC;
            floatx4 a0 = {0.f,0.f,0.f,0.f}, a1 = a0;
            #pragma unroll
            for (int k0 = 0; k0 < CC; k0 += 32) {
                short8 af = *(const short8*)(hsS + swz(lq, k0 + quad * 8, 128));
                short8 b0 = *(const short8*)(W + rB0 + k0 + quad * 8);
                short8 b1 = *(const short8*)(W + rB1 + k0 + quad * 8);
                a0 = __builtin_amdgcn_mfma_f32_16x16x32_bf16(af, b0, a0, 0, 0, 0);
                a1 = __builtin_amdgcn_mfma_f32_16x16x32_bf16(af, b1, a1, 0, 0, 0);
            }
            float bb0 = b1_[n + lq], bb1 = b1_[n + 16 + lq];
            #pragma unroll
            for (int rg = 0; rg < 4; ++rg) {
                int row = quad * 4 + rg;
                ms[swz(row, n + lq, 512)]      = f2bf(gelu_exact(a0[rg] + bb0));
                ms[swz(row, n + 16 + lq, 512)] = f2bf(gelu_exact(a1[rg] + bb1));
            }
        }
    }
    __syncthreads();

    // ---- stage 3: ffn2 (16x32 per wave, K=512 from ms) + res ----
    float w0[4], w1[4];
    {
        const short* msS = (const short*)ms;
        const short* W = (const short*)Wt2_;
        size_t rB0 = (size_t)(n0 + lq) * FFN, rB1 = (size_t)(n0 + 16 + lq) * FFN;
        floatx4 a0 = {0.f,0.f,0.f,0.f}, a1 = a0;
        #pragma unroll 8
        for (int k0 = 0; k0 < FFN; k0 += 32) {
            short8 af = *(const short8*)(msS + swz(lq, k0 + quad * 8, 512));
            short8 b0 = *(const short8*)(W + rB0 + k0 + quad * 8);
            short8 b1 = *(const short8*)(W + rB1 + k0 + quad * 8);
            a0 = __builtin_amdgcn_mfma_f32_16x16x32_bf16(af, b0, a0, 0, 0, 0);
            a1 = __builtin_amdgcn_mfma_f32_16x16x32_bf16(af, b1, a1, 0, 0, 0);
        }
        float bv0 = b2_[c0], bv1 = b2_[c1];
        #pragma unroll
        for (int rg = 0; rg < 4; ++rg) {
            int r = m0 + quad * 4 + rg;
            w0[rg] = a0[rg] + bv0 + vv0[rg];
            w1[rg] = a1[rg] + bv1 + vv1[rg];
            x_[(size_t)r * CC + c0] = w0[rg];
            x_[(size_t)r * CC + c1] = w1[rg];
        }
    }

    if (doQKV) {
        // ln1(next layer) -> hs, then QKV
        #pragma unroll
        for (int rg = 0; rg < 4; ++rg) {
            float s1 = w0[rg] + w1[rg];
            float s2 = w0[rg]*w0[rg] + w1[rg]*w1[rg];
            #pragma unroll
            for (int m = 1; m < 16; m <<= 1) {
                s1 += __shfl_xor(s1, m, 64);
                s2 += __shfl_xor(s2, m, 64);
            }
            if (lq == 0) { sred[wave][quad*4+rg][0] = s1; sred[wave][quad*4+rg][1] = s2; }
        }
        __syncthreads();
        float g0 = ln1g_[c0], g1 = ln1g_[c1], lb0 = ln1b_[c0], lb1 = ln1b_[c1];
        #pragma unroll
        for (int rg = 0; rg < 4; ++rg) {
            int row = quad * 4 + rg;
            float S1 = sred[0][row][0] + sred[1][row][0] + sred[2][row][0] + sred[3][row][0];
            float S2 = sred[0][row][1] + sred[1][row][1] + sred[2][row][1] + sred[3][row][1];
            float mn = S1 * (1.0f/CC);
            float var = S2 * (1.0f/CC) - mn * mn;
            float rs = rsqrtf(var + 1e-5f);
            hs[swz(row, c0, 128)] = f2bf((w0[rg] - mn) * rs * g0 + lb0);
            hs[swz(row, c1, 128)] = f2bf((w1[rg] - mn) * rs * g1 + lb1);
        }
        __syncthreads();
        qkv_stage4(hs, Wtq, bq_, Wtk, bk_, Wtv, bv_, qb, kb, vt, m0, wave, lq, quad);
        return;
    }

    // ---- last layer: folded head for the graph-token row in this tile (if any) ----
    int gb = (m0 + TT - 1) / TT;          // candidate graph whose token row >= m0
    int rgt = gb * TT;
    if (gb >= BB || rgt >= m0 + 16) return;
    int hb = rgt - m0;                    // row within tile

    __syncthreads();                      // all waves done reading ms; reuse as scratch
    float* hrow = (float*)ms;             // 128
    float* xfs  = hrow + CC;              // 128
    float* c1s  = xfs + CC;               // 64
    float* red  = c1s + 64;               // 4
    #pragma unroll
    for (int rg = 0; rg < 4; ++rg) {
        if (quad * 4 + rg == hb) { hrow[c0] = w0[rg]; hrow[c1] = w1[rg]; }
    }
    __syncthreads();

    {
        int c = tid;
        float v = 0.f, s1 = 0.f, s2 = 0.f;
        if (c < CC) { v = hrow[c]; s1 = v; s2 = v * v; }
        #pragma unroll
        for (int m = 32; m >= 1; m >>= 1) {
            s1 += __shfl_xor(s1, m, 64);
            s2 += __shfl_xor(s2, m, 64);
        }
        int w = c >> 6;
        if (c < CC && (c & 63) == 0) { red[w*2] = s1; red[w*2+1] = s2; }
        __syncthreads();
        if (c < CC) {
            float S1 = red[0] + red[2], S2 = red[1] + red[3];
            float mn = S1 * (1.0f/CC);
            float var = S2 * (1.0f/CC) - mn * mn;
            float rs = rsqrtf(var + 1e-5f);
            xfs[c] = (v - mn) * rs * nfg[c] + nfb[c];
        }
        __syncthreads();
        if (c < 64) {
            float acc = bc1[c];
            #pragma unroll 4
            for (int k = 0; k < CC; ++k) acc = fmaf(xfs[k], Wc1[(size_t)k * 64 + c], acc);
            c1s[c] = gelu_exact(acc);
        }
        __syncthreads();
        if (c < NCLS) {
            float acc = bc2[c];
            #pragma unroll 4
            for (int j = 0; j < 64; ++j) acc = fmaf(c1s[j], Wc2[(size_t)j * NCLS + c], acc);
            out[(size_t)gb * NCLS + c] = acc;
        }
    }
}

// ---------------- MFMA fused attention: one block per (bh, 16-query tile) ----------------
__global__ __launch_bounds__(256) void attn_kernel(const ushort_t* __restrict__ qb,
                                                   const ushort_t* __restrict__ kb,
                                                   const ushort_t* __restrict__ vt,
                                                   const int* __restrict__ cnt,
                                                   const int* __restrict__ ebuf,
                                                   const float* __restrict__ ebt,
                                                   const float* __restrict__ vnode,
                                                   ushort_t* __restrict__ ob) {
    int bh = blockIdx.x;
    int qt = blockIdx.y;
    int b = bh >> 3, h = bh & (HH - 1);
    int tid = threadIdx.x;
    int wave = tid >> 6, lane = tid & 63, lq = lane & 15, quad = lane >> 4;

    __shared__ float arena[16 * BSTR];   // strip [q][s] (aliased by epilogue bufs)
    float* bstrip = arena;

    int qg = qt * 16 + lq;
    int qr = qg < TT ? qg : TT - 1;
    short8 qf = {0,0,0,0,0,0,0,0};
    if (quad < 2)
        qf = *(const short8*)(qb + ((size_t)(b * TT + qr)) * CC + h * DD + quad * 8);
    float vbh = vnode[h];
    int ql = tid >> 4, e0 = tid & 15;
    int qs = qt * 16 + ql;
    int crow = b * TT + (qs < TT ? qs : 0);
    int cn = (qs > 0 && qs < TT) ? min(cnt[crow], ECAP) : 0;

    const short* kbS = (const short*)kb;
    const short* vtS = (const short*)(vt + (size_t)bh * DD * SP);

    floatx4 oacc = {0.f, 0.f, 0.f, 0.f};
    float lsum = 0.f;

    #pragma unroll
    for (int ch = 0; ch < 2; ++ch) {
        int sp_lo = ch ? 9 : 0;
        int sp_hi = ch ? 17 : 9;
        int s_lo  = ch ? 288 : 0;
        int nrows = ch ? 256 : 288;

        int sp = sp_lo + wave;
        short8 af0 = {0,0,0,0,0,0,0,0}, af1 = af0, vf = af0;
        if (sp < sp_hi) {
            int st0 = sp * 2, st1 = sp * 2 + 1;
            int kr0 = min(b * TT + st0 * 16 + lq, (int)XROWS - 1);
            int kr1 = min(b * TT + st1 * 16 + lq, (int)XROWS - 1);
            if (quad < 2) {
                af0 = *(const short8*)(kbS + (size_t)kr0 * CC + h * DD + quad * 8);
                af1 = *(const short8*)(kbS + (size_t)kr1 * CC + h * DD + quad * 8);
            }
            vf = *(const short8*)(vtS + (size_t)lq * SP + sp * 32 + quad * 8);
        }

        for (int i = tid; i < 16 * BSTR / 4; i += 256)
            ((float4*)bstrip)[i] = make_float4(0.f, 0.f, 0.f, 0.f);
        __syncthreads();
        if (ch == 0 && tid < 16) {
            int q = qt * 16 + tid;
            if (q > 0 && q < TT) bstrip[tid * BSTR] = vbh;
        }
        for (int j = e0; j < cn; j += 16) {
            int e = ebuf[(size_t)crow * ECAP + j];
            int dl = e & 0xFFFF, a = e >> 16;
            int loc = dl - s_lo;
            if (loc >= 0 && loc < nrows)
                atomicAdd(&bstrip[ql * BSTR + loc], ebt[a * 8 + h]);
        }
        __syncthreads();

        for (; sp < sp_hi; sp += 4) {
            int spn = sp + 4;
            short8 nf0 = {0,0,0,0,0,0,0,0}, nf1 = nf0, nvf = nf0;
            if (spn < sp_hi) {
                int st0 = spn * 2, st1 = spn * 2 + 1;
                int kr0 = min(b * TT + st0 * 16 + lq, (int)XROWS - 1);
                int kr1 = min(b * TT + st1 * 16 + lq, (int)XROWS - 1);
                if (quad < 2) {
                    nf0 = *(const short8*)(kbS + (size_t)kr0 * CC + h * DD + quad * 8);
                    nf1 = *(const short8*)(kbS + (size_t)kr1 * CC + h * DD + quad * 8);
                }
                nvf = *(const short8*)(vtS + (size_t)lq * SP + spn * 32 + quad * 8);
            }

            unsigned pw[2][2];
            #pragma unroll
            for (int t = 0; t < 2; ++t) {
                int st = sp * 2 + t;
                floatx4 c = __builtin_amdgcn_mfma_f32_16x16x32_bf16(
                    t ? af1 : af0, qf, (floatx4){0.f, 0.f, 0.f, 0.f}, 0, 0, 0);
                float4 bi = *(const float4*)(bstrip + lq * BSTR + (st * 16 - s_lo) + quad * 4);
                float biv[4] = {bi.x, bi.y, bi.z, bi.w};
                float pr[4];
                #pragma unroll
                for (int rg = 0; rg < 4; ++rg) {
                    int s = st * 16 + quad * 4 + rg;
                    float p = 0.f;
                    if (s < TT) p = __expf(c[rg] + biv[rg]);
                    lsum += p;
                    pr[rg] = p;
                }
                pw[t][0] = (unsigned)f2bf(pr[0]) | ((unsigned)f2bf(pr[1]) << 16);
                pw[t][1] = (unsigned)f2bf(pr[2]) | ((unsigned)f2bf(pr[3]) << 16);
            }
            int srcA = lq + (((2 * quad) & 3) << 4);
            int srcB = lq + (((2 * quad + 1) & 3) << 4);
            int a00 = __shfl((int)pw[0][0], srcA, 64);
            int a01 = __shfl((int)pw[0][1], srcA, 64);
            int a10 = __shfl((int)pw[1][0], srcA, 64);
            int a11 = __shfl((int)pw[1][1], srcA, 64);
            int b00 = __shfl((int)pw[0][0], srcB, 64);
            int b01 = __shfl((int)pw[0][1], srcB, 64);
            int b10 = __shfl((int)pw[1][0], srcB, 64);
            int b11 = __shfl((int)pw[1][1], srcB, 64);
            union { int u[4]; short8 s8; } pu;
            bool lo = quad < 2;
            pu.u[0] = lo ? a00 : a10;
            pu.u[1] = lo ? a01 : a11;
            pu.u[2] = lo ? b00 : b10;
            pu.u[3] = lo ? b01 : b11;
            oacc = __builtin_amdgcn_mfma_f32_16x16x32_bf16(vf, pu.s8, oacc, 0, 0, 0);

            af0 = nf0; af1 = nf1; vf = nvf;
        }
        __syncthreads();
    }

    lsum += __shfl_xor(lsum, 16, 64);
    lsum += __shfl_xor(lsum, 32, 64);
    float* redw = arena;
    float* lsumS = arena + 1088;
    #pragma unroll
    for (int rg = 0; rg < 4; ++rg)
        redw[wave * 272 + (quad * 4 + rg) * 17 + lq] = oacc[rg];
    if (quad == 0) lsumS[wave * 16 + lq] = lsum;
    __syncthreads();

    {
        int q = tid >> 4, d = tid & 15;
        float o = 0.f, L = 0.f;
        #pragma unroll
        for (int w = 0; w < 4; ++w) {
            o += redw[w * 272 + d * 17 + q];
            L += lsumS[w * 16 + q];
        }
        int qq = qt * 16 + q;
        if (qq < TT)
            ob[((size_t)(b * TT + qq)) * CC + h * DD + d] = f2bf(o / L);
    }
}

extern "C" void kernel_launch(void* const* d_in, const int* in_sizes, int n_in,
                              void* d_out, int out_size, void* d_ws, size_t ws_size,
                              hipStream_t stream) {
    const float* node_feats = (const float*)d_in[0];
    const int*   edge_index = (const int*)d_in[1];
    const int*   edge_attr  = (const int*)d_in[2];
    const float* W_node  = (const float*)d_in[4];
    const float* b_node  = (const float*)d_in[5];
    const float* g_token = (const float*)d_in[6];
    const float* ebt     = (const float*)d_in[7];
    const float* ide     = (const float*)d_in[8];
    const float* ode     = (const float*)d_in[9];
    const float* vnode   = (const float*)d_in[10];
    const float* Wq = (const float*)d_in[11];
    const float* bq = (const float*)d_in[12];
    const float* Wk = (const float*)d_in[13];
    const float* bk = (const float*)d_in[14];
    const float* Wv = (const float*)d_in[15];
    const float* bv = (const float*)d_in[16];
    const float* Wo = (const float*)d_in[17];
    const float* bo = (const float*)d_in[18];
    const float* ln1g = (const float*)d_in[19];
    const float* ln1b = (const float*)d_in[20];
    const float* ln2g = (const float*)d_in[21];
    const float* ln2b = (const float*)d_in[22];
    const float* W1 = (const float*)d_in[23];
    const float* b1 = (const float*)d_in[24];
    const float* W2 = (const float*)d_in[25];
    const float* b2 = (const float*)d_in[26];
    const float* nfg = (const float*)d_in[27];
    const float* nfb = (const float*)d_in[28];
    const float* Wc1 = (const float*)d_in[29];
    const float* bc1 = (const float*)d_in[30];
    const float* Wc2 = (const float*)d_in[31];
    const float* bc2 = (const float*)d_in[32];
    float* out = (float*)d_out;

    // ---- workspace (all chunks 16B-aligned) ----
    char* base = (char*)d_ws;
    float* x      = (float*)base;     base += XSZ * 4;
    ushort_t* qb  = (ushort_t*)base;  base += XSZ * 2;
    ushort_t* kb  = (ushort_t*)base;  base += XSZ * 2;
    ushort_t* vt  = (ushort_t*)base;  base += VTSZ * 2;
    ushort_t* obf = (ushort_t*)base;  base += XSZ * 2;
    ushort_t* wtqkvo = (ushort_t*)base; base += (size_t)16 * 16384 * 2;
    ushort_t* wt1 = (ushort_t*)base;  base += (size_t)4 * 65536 * 2;
    ushort_t* wt2 = (ushort_t*)base;  base += (size_t)4 * 65536 * 2;
    int* deg_in  = (int*)base;        base += NNODES * 4;
    int* deg_out = (int*)base;        base += NNODES * 4;
    int* cnt     = (int*)base;        base += (size_t)ROWS * 4;
    int* ebuf    = (int*)base;        base += (size_t)ROWS * ECAP * 4;

    const int MT16 = (int)(XROWS / 16);   // 513 m-tiles of 16 rows (exact)

    hipMemsetAsync(deg_in, 0, (size_t)(2 * NNODES + ROWS) * 4, stream);
    deg_csr_tr_kernel<<<512 + 192, 256, 0, stream>>>(
        edge_index, edge_attr, deg_in, deg_out, cnt, ebuf,
        Wq, Wk, Wv, Wo, W1, W2, wtqkvo, wt1, wt2);

    encode_pre_kernel<<<MT16, 256, 0, stream>>>(
        node_feats, W_node, b_node, g_token, ide, ode, deg_in, deg_out,
        ln1g, ln1b, wtqkvo, bq, bk, bv, x, qb, kb, vt);

    for (int l = 0; l < LL; ++l) {
        attn_kernel<<<dim3(BB*HH, 33), 256, 0, stream>>>(
            qb, kb, vt, cnt, ebuf, ebt, vnode, obf);

        int ln = (l + 1) % LL;   // next layer (unused when l==LL-1)
        mega_kernel<<<MT16, 256, 0, stream>>>(
            obf,
            wtqkvo + (size_t)(12 + l)*16384, bo + l*CC,
            ln2g + l*CC, ln2b + l*CC,
            wt1 + (size_t)l*65536, b1 + l*FFN,
            wt2 + (size_t)l*65536, b2 + l*CC,
            ln1g + ln*CC, ln1b + ln*CC,
            wtqkvo + (size_t)(0 + ln)*16384, bq + ln*CC,
            wtqkvo + (size_t)(4 + ln)*16384, bk + ln*CC,
            wtqkvo + (size_t)(8 + ln)*16384, bv + ln*CC,
            nfg, nfb, Wc1, bc1, Wc2, bc2,
            x, qb, kb, vt, out,
            (l < LL-1) ? 1 : 0);
    }
}